// Round 11
// baseline (173.159 us; speedup 1.0000x reference)
//
#include <hip/hip_runtime.h>

#define PITCH 72   // bf16 pitch for MFMA planes: 144 B rows, 16B-aligned
#define QKV_STRIDE 12288   // shorts per (n,i): 192 ch x 64 j

typedef __attribute__((ext_vector_type(8))) short short8v;
typedef __attribute__((ext_vector_type(4))) short short4v;
typedef __attribute__((ext_vector_type(4))) float f32x4;

// ---------------- bf16 helpers -----------------------------------------------
__device__ __forceinline__ short f2bf(float v) {
    unsigned u = __builtin_bit_cast(unsigned, v);
    unsigned r = (u + 0x7FFFu + ((u >> 16) & 1u)) >> 16;
    return (short)r;
}
__device__ __forceinline__ float bf2f(short s) {
    unsigned u = ((unsigned)(unsigned short)s) << 16;
    return __builtin_bit_cast(float, u);
}

#define MFMA(a, b, c) __builtin_amdgcn_mfma_f32_16x16x32_bf16(a, b, c, 0, 0, 0)

// A/B fragment from LDS plane (pitch 72)
__device__ __forceinline__ short8v ldfrag(const short* p, int rowtile, int kc, int l) {
    return *(const short8v*)&p[(rowtile * 16 + (l & 15)) * PITCH + kc * 32 + (l >> 4) * 8];
}
// fragment from global row-major [rows][64]
__device__ __forceinline__ short8v gfrag(const short* __restrict__ p, int rowtile, int kc, int l) {
    return *(const short8v*)&p[(rowtile * 16 + (l & 15)) * 64 + kc * 32 + (l >> 4) * 8];
}
// fragment from global with custom row stride (for [n][i][ch][j] gathers)
__device__ __forceinline__ short8v gfrag_s(const short* __restrict__ p, int rowtile,
                                           int kc, int l, int stride) {
    return *(const short8v*)&p[(rowtile * 16 + (l & 15)) * stride + kc * 32 + (l >> 4) * 8];
}

// D = X·Y^T, hi-only, X,Y in LDS
__device__ __forceinline__ void p1(const short* xh, const short* yh,
                                   int w, int l, f32x4 (&acc)[4]) {
#pragma unroll
    for (int ct = 0; ct < 4; ++ct) acc[ct] = (f32x4){0.f, 0.f, 0.f, 0.f};
#pragma unroll
    for (int kc = 0; kc < 2; ++kc) {
        short8v aH = ldfrag(xh, w, kc, l);
#pragma unroll
        for (int ct = 0; ct < 4; ++ct)
            acc[ct] = MFMA(aH, ldfrag(yh, ct, kc, l), acc[ct]);
    }
}

// D = X·Y^T, hi-only, X from GLOBAL with row stride
__device__ __forceinline__ void p1_g(const short* __restrict__ xg, const short* yh,
                                     int w, int l, f32x4 (&acc)[4]) {
#pragma unroll
    for (int ct = 0; ct < 4; ++ct) acc[ct] = (f32x4){0.f, 0.f, 0.f, 0.f};
#pragma unroll
    for (int kc = 0; kc < 2; ++kc) {
        short8v aH = gfrag_s(xg, w, kc, l, QKV_STRIDE);
#pragma unroll
        for (int ct = 0; ct < 4; ++ct)
            acc[ct] = MFMA(aH, ldfrag(yh, ct, kc, l), acc[ct]);
    }
}

// pack-store D transposed, hi only: z[n][m] = bf16(D[m][n])
__device__ __forceinline__ void pack1(const f32x4 (&acc)[4], short* zh, int w, int l) {
    int m0 = w * 16 + (l >> 4) * 4;
#pragma unroll
    for (int ct = 0; ct < 4; ++ct) {
        int n = ct * 16 + (l & 15);
        short4v h;
#pragma unroll
        for (int r = 0; r < 4; ++r) h[r] = f2bf(acc[ct][r]);
        *(short4v*)&zh[n * PITCH + m0] = h;
    }
}

// in-place exact transpose of ONE plane via identity-MFMA (1 internal barrier)
__device__ __forceinline__ void idtrans_ip1(short* pa, int w, int l) {
    short8v a0 = ldfrag(pa, w, 0, l);
    short8v a1 = ldfrag(pa, w, 1, l);
    short8v I0, I1;
#pragma unroll
    for (int j = 0; j < 8; ++j) {
        int bit = 8 * (l >> 4) + j;
        I0[j] = (bit == (l & 15))      ? (short)0x3F80 : (short)0;
        I1[j] = (bit == (l & 15) + 16) ? (short)0x3F80 : (short)0;
    }
    __syncthreads();
    int m0 = w * 16 + (l >> 4) * 4;
    const f32x4 z4 = {0.f, 0.f, 0.f, 0.f};
#pragma unroll
    for (int s = 0; s < 4; ++s) {
        f32x4 d = MFMA((s >> 1) ? a1 : a0, (s & 1) ? I1 : I0, z4);
        short4v ha;
#pragma unroll
        for (int r = 0; r < 4; ++r) ha[r] = f2bf(d[r]);   // exact: values are bf16
        *(short4v*)&pa[(s * 16 + (l & 15)) * PITCH + m0] = ha;
    }
}

// ---------------- K0: inv_diag + w3T (merged) ---------------------------------
__global__ __launch_bounds__(256) void k0_prep(const float* __restrict__ x,
                                               const float* __restrict__ wq,
                                               const float* __restrict__ wk,
                                               const float* __restrict__ wv,
                                               float* __restrict__ invd,
                                               short* __restrict__ w3h) {
    int b = blockIdx.x;
    if (b < 1024) {
        int t = b * 256 + threadIdx.x;
        int nc = t >> 6, k = t & 63;
        float v = fabsf(x[(size_t)nc * 4096 + (size_t)k * 65]);
        invd[t] = rsqrtf(fmaxf(v, 1e-4f));
    } else {
        int idx = (b - 1024) * 256 + threadIdx.x;   // [0, 12288)
        int co = idx >> 6, c = idx & 63;
        const float* w = (co < 64) ? wq : (co < 128) ? wk : wv;
        w3h[idx] = f2bf(w[c * 64 + (co & 63)]);
    }
}

// ---------------- K1: cov2cor + channel mixing (hi-only), slim LDS ------------
// Block (n,i): D[j][co] = sum_c corT[j][c]*w3T[co][c]. Two 96-row pack+copy
// passes through a 13.8KB z-buffer (cor aliased) -> 8 blocks/CU, linear writes.
__global__ __launch_bounds__(256, 8) void k1_mix_mfma(
    const float* __restrict__ x, const float* __restrict__ invd,
    const short* __restrict__ w3h,
    short* __restrict__ QKV)
{
    __shared__ __align__(16) short smem[6912];    // 13,824 B; cor in [0,4608)
    short* ch = smem;

    const int b = blockIdx.x, n = b >> 6, i = b & 63;
    const int t = threadIdx.x, l = t & 63, w = t >> 6;
    const size_t nbase = (size_t)n * 64;

    // stage cor hi plane [c][j]
#pragma unroll
    for (int rep = 0; rep < 4; ++rep) {
        int id = rep * 256 + t;                 // 1024 float4 chunks
        int c = id >> 4, j4 = (id & 15) * 4;
        float4 xv = *(const float4*)&x[((nbase + c) * 64 + i) * 64 + j4];
        float ii = invd[(nbase + c) * 64 + i];
        float4 jv = *(const float4*)&invd[(nbase + c) * 64 + j4];
        float vv[4] = {xv.x * ii * jv.x, xv.y * ii * jv.y,
                       xv.z * ii * jv.z, xv.w * ii * jv.w};
        short4v h;
#pragma unroll
        for (int r = 0; r < 4; ++r)
            h[r] = f2bf(fminf(1.0f, fmaxf(-1.0f, vv[r])));
        *(short4v*)&ch[c * PITCH + j4] = h;
    }
    __syncthreads();
    idtrans_ip1(ch, w, l);       // cor -> corT in place (1 internal barrier)
    __syncthreads();

    // wave w: co-tiles ct = 3w..3w+2, all 4 j-tiles
    f32x4 acc[4][3];
#pragma unroll
    for (int jt = 0; jt < 4; ++jt)
#pragma unroll
        for (int cc = 0; cc < 3; ++cc) acc[jt][cc] = (f32x4){0.f, 0.f, 0.f, 0.f};
#pragma unroll
    for (int kc = 0; kc < 2; ++kc) {
#pragma unroll
        for (int cc = 0; cc < 3; ++cc) {
            short8v bH = gfrag(w3h, w * 3 + cc, kc, l);
#pragma unroll
            for (int jt = 0; jt < 4; ++jt) {
                short8v aH = ldfrag(ch, jt, kc, l);
                acc[jt][cc] = MFMA(aH, bH, acc[jt][cc]);
            }
        }
    }
    __syncthreads();   // all cor reads done; smem becomes z[96][72]

    const int m0 = (l >> 4) * 4, nb = l & 15;
    short* dst = QKV + (size_t)b * QKV_STRIDE;

    // ---- pass A: tiles 0..5 (waves 0,1) -> z rows 0..95; linear 12KB copy ----
    if (w < 2) {
#pragma unroll
        for (int cc = 0; cc < 3; ++cc) {
            int zrow = (w * 3 + cc) * 16 + nb;
#pragma unroll
            for (int jt = 0; jt < 4; ++jt) {
                short4v h;
#pragma unroll
                for (int r = 0; r < 4; ++r) h[r] = f2bf(acc[jt][cc][r]);
                *(short4v*)&smem[zrow * PITCH + jt * 16 + m0] = h;
            }
        }
    }
    __syncthreads();
#pragma unroll
    for (int rep = 0; rep < 3; ++rep) {
        int id = rep * 256 + t;                 // 768 chunks of 8 shorts
        *(short8v*)&dst[id * 8] = *(short8v*)&smem[(id >> 3) * PITCH + (id & 7) * 8];
    }
    __syncthreads();

    // ---- pass B: tiles 6..11 (waves 2,3) -> z rows 0..95; linear 12KB copy ----
    if (w >= 2) {
#pragma unroll
        for (int cc = 0; cc < 3; ++cc) {
            int zrow = ((w - 2) * 3 + cc) * 16 + nb;
#pragma unroll
            for (int jt = 0; jt < 4; ++jt) {
                short4v h;
#pragma unroll
                for (int r = 0; r < 4; ++r) h[r] = f2bf(acc[jt][cc][r]);
                *(short4v*)&smem[zrow * PITCH + jt * 16 + m0] = h;
            }
        }
    }
    __syncthreads();
#pragma unroll
    for (int rep = 0; rep < 3; ++rep) {
        int id = rep * 256 + t;
        *(short8v*)&dst[6144 + id * 8] =
            *(short8v*)&smem[(id >> 3) * PITCH + (id & 7) * 8];
    }
}

// ---------------- K2: per-(n,c) attention chain, 2 LDS planes -----------------
// Q,K,V,Z1,z4,A all hi-only bf16 (z4 was already bf16-quantized; A-lo dropped).
__global__ __launch_bounds__(256, 6) void k2_attn_mfma(
    const float* __restrict__ x,
    const short* __restrict__ QKV,
    float* __restrict__ out)
{
    // P[0]: K -> Kt -> z4 ; P[1]: Z1 -> A
    __shared__ __align__(16) short P[2][4608];
    __shared__ float part[4][64];
    __shared__ float invs[64];
    __shared__ float red[4];

    const int t = threadIdx.x, l = t & 63, w = t >> 6;
    const int nc = blockIdx.x, n = nc >> 6, c = nc & 63;
    const size_t gbase = (size_t)nc * 4096;

    const short* qh = QKV + (size_t)n * 64 * QKV_STRIDE + (size_t)c * 64;
    const short* kh = qh + 64 * 64;          // ch = 64 + c
    const short* vh = qh + 128 * 64;         // ch = 128 + c

    // stage K hi (rows stride 24KB)
#pragma unroll
    for (int rep = 0; rep < 4; ++rep) {
        int id = rep * 256 + t;
        int r = id >> 4, c4 = (id & 15) * 4;
        *(short4v*)&P[0][r * PITCH + c4] =
            *(const short4v*)&kh[r * QKV_STRIDE + c4];
    }
    __syncthreads();

    idtrans_ip1(P[0], w, l);   // K -> Kt in place
    __syncthreads();

    f32x4 acc[4];

    // Z1 = Q(global) · Kt^T  -> pack into P1
    p1_g(qh, P[0], w, l, acc);
    pack1(acc, P[1], w, l);
    __syncthreads();

    // Pt = Z1 · Kt^T (in registers)
    p1(P[1], P[0], w, l, acc);

    // ---- soft_pd_max ----
    float mx = -1e30f;
#pragma unroll
    for (int ct = 0; ct < 4; ++ct)
#pragma unroll
        for (int r = 0; r < 4; ++r) mx = fmaxf(mx, acc[ct][r]);
#pragma unroll
    for (int off = 1; off < 64; off <<= 1) mx = fmaxf(mx, __shfl_xor(mx, off));
    if (l == 0) red[w] = mx;
    __syncthreads();
    mx = fmaxf(fmaxf(red[0], red[1]), fmaxf(red[2], red[3]));

    float e[4][4];
    float cs[4];
#pragma unroll
    for (int ct = 0; ct < 4; ++ct) {
        float s = 0.f;
#pragma unroll
        for (int r = 0; r < 4; ++r) {
            float ev = __expf(acc[ct][r] - mx);
            e[ct][r] = ev;
            s += ev;
        }
        cs[ct] = s;
    }
#pragma unroll
    for (int ct = 0; ct < 4; ++ct) {
        cs[ct] += __shfl_xor(cs[ct], 16);
        cs[ct] += __shfl_xor(cs[ct], 32);
    }
    if (l < 16) {
#pragma unroll
        for (int ct = 0; ct < 4; ++ct) part[w][ct * 16 + l] = cs[ct];
    }
    __syncthreads();
    if (t < 64) {
        float dia = part[0][t] + part[1][t] + part[2][t] + part[3][t];
        float tot = dia;
#pragma unroll
        for (int off = 1; off < 64; off <<= 1) tot += __shfl_xor(tot, off);
        dia = fmaxf(dia, tot / 100000.0f);
        dia = fmaxf(dia, 1e-5f);
        invs[t] = rsqrtf(dia);
    }
    __syncthreads();

    // A[m][n] = e*inv*inv -> P1 hi-only (Z1 dead; softmax barriers fence)
    {
        int m0 = w * 16 + (l >> 4) * 4;
        float ir[4] = {invs[m0], invs[m0 + 1], invs[m0 + 2], invs[m0 + 3]};
        int nb = l & 15;
#pragma unroll
        for (int ct = 0; ct < 4; ++ct) {
            float ic = invs[ct * 16 + nb];
            short4v h;
#pragma unroll
            for (int r = 0; r < 4; ++r)
                h[r] = f2bf(e[ct][r] * ir[r] * ic);
            *(short4v*)&P[1][(ct * 16 + nb) * PITCH + m0] = h;
        }
    }
    __syncthreads();

    // z4 = V(global) · A^T -> pack into P0 (Kt dead)
    p1_g(vh, P[1], w, l, acc);
    pack1(acc, P[0], w, l);
    __syncthreads();

    // OUT = A · z4^T = A V A^T
    p1(P[1], P[0], w, l, acc);
    __syncthreads();   // all plane reads done; alias as f32 out-stage

    // stage out tile f32 [64][68] over P (17,408 B of 18,432), then store
    {
        float* ofs = (float*)&P[0][0];
        int m0 = w * 16 + (l >> 4) * 4;
        int nb = l & 15;
#pragma unroll
        for (int ct = 0; ct < 4; ++ct)
#pragma unroll
            for (int r = 0; r < 4; ++r)
                ofs[(m0 + r) * 68 + ct * 16 + nb] = acc[ct][r];
    }
    __syncthreads();
    {
        const float* ofs = (const float*)&P[0][0];
#pragma unroll
        for (int rep = 0; rep < 4; ++rep) {
            int id = rep * 256 + t;
            int row = id >> 4, c4 = (id & 15) * 4;
            float4 v  = *(const float4*)&ofs[row * 68 + c4];
            float4 xv = *(const float4*)&x[gbase + (size_t)row * 64 + c4];
            *(float4*)&out[gbase + (size_t)row * 64 + c4] =
                make_float4(xv.x + v.x, xv.y + v.y, xv.z + v.z, xv.w + v.w);
        }
    }
}

// ---------------- launch -----------------------------------------------------
extern "C" void kernel_launch(void* const* d_in, const int* in_sizes, int n_in,
                              void* d_out, int out_size, void* d_ws, size_t ws_size,
                              hipStream_t stream) {
    const float* x  = (const float*)d_in[0];
    const float* wq = (const float*)d_in[1];
    const float* wk = (const float*)d_in[2];
    const float* wv = (const float*)d_in[3];
    float* out = (float*)d_out;

    char* wsb = (char*)d_ws;
    float* invd = (float*)wsb;                       // 1 MB
    short* w3h  = (short*)(wsb + (1 << 20));         // 24 KB
    short* QKV  = (short*)(wsb + (2 << 20));         // 96 MB, [n][i][192ch][j]

    k0_prep<<<1072, 256, 0, stream>>>(x, wq, wk, wv, invd, w3h);
    k1_mix_mfma<<<4096, 256, 0, stream>>>(x, invd, w3h, QKV);
    k2_attn_mfma<<<4096, 256, 0, stream>>>(x, QKV, out);
}

// Round 12
// 79.954 us; speedup vs baseline: 2.1657x; 2.1657x over previous
//
#include <hip/hip_runtime.h>

#define PITCH 72   // bf16 pitch for MFMA planes: 144 B rows, 16B-aligned
#define QKV_STRIDE 12288   // shorts per (n,i): 192 ch x 64 j

typedef __attribute__((ext_vector_type(8))) short short8v;
typedef __attribute__((ext_vector_type(4))) short short4v;
typedef __attribute__((ext_vector_type(4))) float f32x4;

// ---------------- bf16 helpers -----------------------------------------------
__device__ __forceinline__ short f2bf(float v) {
    unsigned u = __builtin_bit_cast(unsigned, v);
    unsigned r = (u + 0x7FFFu + ((u >> 16) & 1u)) >> 16;
    return (short)r;
}
__device__ __forceinline__ float bf2f(short s) {
    unsigned u = ((unsigned)(unsigned short)s) << 16;
    return __builtin_bit_cast(float, u);
}

#define MFMA(a, b, c) __builtin_amdgcn_mfma_f32_16x16x32_bf16(a, b, c, 0, 0, 0)

// A/B fragment from LDS plane (pitch 72)
__device__ __forceinline__ short8v ldfrag(const short* p, int rowtile, int kc, int l) {
    return *(const short8v*)&p[(rowtile * 16 + (l & 15)) * PITCH + kc * 32 + (l >> 4) * 8];
}
// fragment from global row-major [rows][64]
__device__ __forceinline__ short8v gfrag(const short* __restrict__ p, int rowtile, int kc, int l) {
    return *(const short8v*)&p[(rowtile * 16 + (l & 15)) * 64 + kc * 32 + (l >> 4) * 8];
}
// fragment from global with custom row stride (for [n][i][ch][j] gathers)
__device__ __forceinline__ short8v gfrag_s(const short* __restrict__ p, int rowtile,
                                           int kc, int l, int stride) {
    return *(const short8v*)&p[(rowtile * 16 + (l & 15)) * stride + kc * 32 + (l >> 4) * 8];
}

// D = X·Y^T, hi-only, X,Y in LDS
__device__ __forceinline__ void p1(const short* xh, const short* yh,
                                   int w, int l, f32x4 (&acc)[4]) {
#pragma unroll
    for (int ct = 0; ct < 4; ++ct) acc[ct] = (f32x4){0.f, 0.f, 0.f, 0.f};
#pragma unroll
    for (int kc = 0; kc < 2; ++kc) {
        short8v aH = ldfrag(xh, w, kc, l);
#pragma unroll
        for (int ct = 0; ct < 4; ++ct)
            acc[ct] = MFMA(aH, ldfrag(yh, ct, kc, l), acc[ct]);
    }
}

// D = X·Y^T, hi-only, X from GLOBAL with row stride
__device__ __forceinline__ void p1_g(const short* __restrict__ xg, const short* yh,
                                     int w, int l, f32x4 (&acc)[4]) {
#pragma unroll
    for (int ct = 0; ct < 4; ++ct) acc[ct] = (f32x4){0.f, 0.f, 0.f, 0.f};
#pragma unroll
    for (int kc = 0; kc < 2; ++kc) {
        short8v aH = gfrag_s(xg, w, kc, l, QKV_STRIDE);
#pragma unroll
        for (int ct = 0; ct < 4; ++ct)
            acc[ct] = MFMA(aH, ldfrag(yh, ct, kc, l), acc[ct]);
    }
}

// pack-store D transposed, hi only: z[n][m] = bf16(D[m][n])
__device__ __forceinline__ void pack1(const f32x4 (&acc)[4], short* zh, int w, int l) {
    int m0 = w * 16 + (l >> 4) * 4;
#pragma unroll
    for (int ct = 0; ct < 4; ++ct) {
        int n = ct * 16 + (l & 15);
        short4v h;
#pragma unroll
        for (int r = 0; r < 4; ++r) h[r] = f2bf(acc[ct][r]);
        *(short4v*)&zh[n * PITCH + m0] = h;
    }
}

// in-place exact transpose of ONE plane via identity-MFMA (1 internal barrier)
__device__ __forceinline__ void idtrans_ip1(short* pa, int w, int l) {
    short8v a0 = ldfrag(pa, w, 0, l);
    short8v a1 = ldfrag(pa, w, 1, l);
    short8v I0, I1;
#pragma unroll
    for (int j = 0; j < 8; ++j) {
        int bit = 8 * (l >> 4) + j;
        I0[j] = (bit == (l & 15))      ? (short)0x3F80 : (short)0;
        I1[j] = (bit == (l & 15) + 16) ? (short)0x3F80 : (short)0;
    }
    __syncthreads();
    int m0 = w * 16 + (l >> 4) * 4;
    const f32x4 z4 = {0.f, 0.f, 0.f, 0.f};
#pragma unroll
    for (int s = 0; s < 4; ++s) {
        f32x4 d = MFMA((s >> 1) ? a1 : a0, (s & 1) ? I1 : I0, z4);
        short4v ha;
#pragma unroll
        for (int r = 0; r < 4; ++r) ha[r] = f2bf(d[r]);   // exact: values are bf16
        *(short4v*)&pa[(s * 16 + (l & 15)) * PITCH + m0] = ha;
    }
}

// in-place exact transpose of TWO planes (1 internal barrier)
__device__ __forceinline__ void idtrans_ip2(short* pa, short* pb, int w, int l) {
    short8v a0 = ldfrag(pa, w, 0, l);
    short8v a1 = ldfrag(pa, w, 1, l);
    short8v b0 = ldfrag(pb, w, 0, l);
    short8v b1 = ldfrag(pb, w, 1, l);
    short8v I0, I1;
#pragma unroll
    for (int j = 0; j < 8; ++j) {
        int bit = 8 * (l >> 4) + j;
        I0[j] = (bit == (l & 15))      ? (short)0x3F80 : (short)0;
        I1[j] = (bit == (l & 15) + 16) ? (short)0x3F80 : (short)0;
    }
    __syncthreads();
    int m0 = w * 16 + (l >> 4) * 4;
    const f32x4 z4 = {0.f, 0.f, 0.f, 0.f};
#pragma unroll
    for (int s = 0; s < 4; ++s) {
        f32x4 d = MFMA((s >> 1) ? a1 : a0, (s & 1) ? I1 : I0, z4);
        f32x4 e = MFMA((s >> 1) ? b1 : b0, (s & 1) ? I1 : I0, z4);
        short4v ha, hb2;
#pragma unroll
        for (int r = 0; r < 4; ++r) { ha[r] = f2bf(d[r]); hb2[r] = f2bf(e[r]); }
        int drow = s * 16 + (l & 15);
        *(short4v*)&pa[drow * PITCH + m0] = ha;
        *(short4v*)&pb[drow * PITCH + m0] = hb2;
    }
}

// ---------------- K0: inv_diag + w3T (merged) ---------------------------------
__global__ __launch_bounds__(256) void k0_prep(const float* __restrict__ x,
                                               const float* __restrict__ wq,
                                               const float* __restrict__ wk,
                                               const float* __restrict__ wv,
                                               float* __restrict__ invd,
                                               short* __restrict__ w3h) {
    int b = blockIdx.x;
    if (b < 1024) {
        int t = b * 256 + threadIdx.x;
        int nc = t >> 6, k = t & 63;
        float v = fabsf(x[(size_t)nc * 4096 + (size_t)k * 65]);
        invd[t] = rsqrtf(fmaxf(v, 1e-4f));
    } else {
        int idx = (b - 1024) * 256 + threadIdx.x;   // [0, 12288)
        int co = idx >> 6, c = idx & 63;
        const float* w = (co < 64) ? wq : (co < 128) ? wk : wv;
        w3h[idx] = f2bf(w[c * 64 + (co & 63)]);
    }
}

// ---------------- K1: cov2cor + channel mixing, i-PAIR, dense copy-out --------
// (R10 structure verbatim: proven 43.5us, VGPR 84, no spill.)
__global__ __launch_bounds__(256, 3) void k1_mix_mfma(
    const float* __restrict__ x, const float* __restrict__ invd,
    const short* __restrict__ w3h,
    short* __restrict__ QKV)
{
    __shared__ __align__(16) short smem[13824];   // 27,648 B
    short* ch0 = smem;                            // cor hi i0 [64][72]
    short* ch1 = smem + 4608;                     // cor hi i1
    short* z   = smem;                            // pack stage [192][72] (alias)

    const int b = blockIdx.x, n = b >> 5, ip = b & 31;
    const int t = threadIdx.x, l = t & 63, w = t >> 6;
    const size_t nbase = (size_t)n * 64;
    const int i0 = ip * 2;

    // stage two cor planes [c][j]
#pragma unroll
    for (int rep = 0; rep < 8; ++rep) {
        int id = rep * 256 + t;                 // 2048 float4 chunks
        int isel = id >> 10, rem = id & 1023;
        int c = rem >> 4, j4 = (rem & 15) * 4;
        int i = i0 + isel;
        float4 xv = *(const float4*)&x[((nbase + c) * 64 + i) * 64 + j4];
        float ii = invd[(nbase + c) * 64 + i];
        float4 jv = *(const float4*)&invd[(nbase + c) * 64 + j4];
        float vv[4] = {xv.x * ii * jv.x, xv.y * ii * jv.y,
                       xv.z * ii * jv.z, xv.w * ii * jv.w};
        short4v h;
#pragma unroll
        for (int r = 0; r < 4; ++r)
            h[r] = f2bf(fminf(1.0f, fmaxf(-1.0f, vv[r])));
        short* dst = isel ? ch1 : ch0;
        *(short4v*)&dst[c * PITCH + j4] = h;
    }
    __syncthreads();
    idtrans_ip2(ch0, ch1, w, l);   // both cor -> corT in place
    __syncthreads();

    // wave w: co-tiles 3w..3w+2, 4 j-tiles, both i (B-frags shared)
    f32x4 a0[4][3], a1[4][3];
#pragma unroll
    for (int jt = 0; jt < 4; ++jt)
#pragma unroll
        for (int cc = 0; cc < 3; ++cc) {
            a0[jt][cc] = (f32x4){0.f, 0.f, 0.f, 0.f};
            a1[jt][cc] = (f32x4){0.f, 0.f, 0.f, 0.f};
        }
#pragma unroll
    for (int kc = 0; kc < 2; ++kc) {
        short8v f0[4], f1[4];
#pragma unroll
        for (int jt = 0; jt < 4; ++jt) {
            f0[jt] = ldfrag(ch0, jt, kc, l);
            f1[jt] = ldfrag(ch1, jt, kc, l);
        }
#pragma unroll
        for (int cc = 0; cc < 3; ++cc) {
            short8v bH = gfrag(w3h, w * 3 + cc, kc, l);
#pragma unroll
            for (int jt = 0; jt < 4; ++jt) {
                a0[jt][cc] = MFMA(f0[jt], bH, a0[jt][cc]);
                a1[jt][cc] = MFMA(f1[jt], bH, a1[jt][cc]);
            }
        }
    }
    __syncthreads();   // all cor reads done; z (alias) is free

    const int m0 = (l >> 4) * 4, nb = l & 15;
    short* dst0 = QKV + (size_t)(nbase + i0) * QKV_STRIDE;

    // ---- pass A: pack i0 -> z, dense 24KB copy ----
#pragma unroll
    for (int cc = 0; cc < 3; ++cc) {
        int nrow = (w * 3 + cc) * 16 + nb;
#pragma unroll
        for (int jt = 0; jt < 4; ++jt) {
            short4v h;
#pragma unroll
            for (int r = 0; r < 4; ++r) h[r] = f2bf(a0[jt][cc][r]);
            *(short4v*)&z[nrow * PITCH + jt * 16 + m0] = h;
        }
    }
    __syncthreads();
#pragma unroll
    for (int rep = 0; rep < 6; ++rep) {
        int id = rep * 256 + t;                 // 1536 chunks of 8 shorts
        *(short8v*)&dst0[id * 8] = *(short8v*)&z[(id >> 3) * PITCH + (id & 7) * 8];
    }
    __syncthreads();   // copy reads done before pass B overwrites z

    // ---- pass B: pack i1 -> z, dense 24KB copy ----
#pragma unroll
    for (int cc = 0; cc < 3; ++cc) {
        int nrow = (w * 3 + cc) * 16 + nb;
#pragma unroll
        for (int jt = 0; jt < 4; ++jt) {
            short4v h;
#pragma unroll
            for (int r = 0; r < 4; ++r) h[r] = f2bf(a1[jt][cc][r]);
            *(short4v*)&z[nrow * PITCH + jt * 16 + m0] = h;
        }
    }
    __syncthreads();
#pragma unroll
    for (int rep = 0; rep < 6; ++rep) {
        int id = rep * 256 + t;
        *(short8v*)&dst0[QKV_STRIDE + id * 8] =
            *(short8v*)&z[(id >> 3) * PITCH + (id & 7) * 8];
    }
}

// ---------------- K2: per-(n,c) attention chain, 2 LDS planes -----------------
// Q,K,V,Z1,z4,A all hi-only bf16. bounds(256,5): VGPR cap 102, no spill risk.
__global__ __launch_bounds__(256, 5) void k2_attn_mfma(
    const float* __restrict__ x,
    const short* __restrict__ QKV,
    float* __restrict__ out)
{
    // P[0]: K -> Kt -> z4 ; P[1]: Z1 -> A
    __shared__ __align__(16) short P[2][4608];
    __shared__ float part[4][64];
    __shared__ float invs[64];
    __shared__ float red[4];

    const int t = threadIdx.x, l = t & 63, w = t >> 6;
    const int nc = blockIdx.x, n = nc >> 6, c = nc & 63;
    const size_t gbase = (size_t)nc * 4096;

    const short* qh = QKV + (size_t)n * 64 * QKV_STRIDE + (size_t)c * 64;
    const short* kh = qh + 64 * 64;          // ch = 64 + c
    const short* vh = qh + 128 * 64;         // ch = 128 + c

    // stage K hi (rows stride 24KB)
#pragma unroll
    for (int rep = 0; rep < 4; ++rep) {
        int id = rep * 256 + t;
        int r = id >> 4, c4 = (id & 15) * 4;
        *(short4v*)&P[0][r * PITCH + c4] =
            *(const short4v*)&kh[r * QKV_STRIDE + c4];
    }
    __syncthreads();

    idtrans_ip1(P[0], w, l);   // K -> Kt in place
    __syncthreads();

    f32x4 acc[4];

    // Z1 = Q(global) · Kt^T  -> pack into P1
    p1_g(qh, P[0], w, l, acc);
    pack1(acc, P[1], w, l);
    __syncthreads();

    // Pt = Z1 · Kt^T (in registers)
    p1(P[1], P[0], w, l, acc);

    // ---- soft_pd_max ----
    float mx = -1e30f;
#pragma unroll
    for (int ct = 0; ct < 4; ++ct)
#pragma unroll
        for (int r = 0; r < 4; ++r) mx = fmaxf(mx, acc[ct][r]);
#pragma unroll
    for (int off = 1; off < 64; off <<= 1) mx = fmaxf(mx, __shfl_xor(mx, off));
    if (l == 0) red[w] = mx;
    __syncthreads();
    mx = fmaxf(fmaxf(red[0], red[1]), fmaxf(red[2], red[3]));

    float e[4][4];
    float cs[4];
#pragma unroll
    for (int ct = 0; ct < 4; ++ct) {
        float s = 0.f;
#pragma unroll
        for (int r = 0; r < 4; ++r) {
            float ev = __expf(acc[ct][r] - mx);
            e[ct][r] = ev;
            s += ev;
        }
        cs[ct] = s;
    }
#pragma unroll
    for (int ct = 0; ct < 4; ++ct) {
        cs[ct] += __shfl_xor(cs[ct], 16);
        cs[ct] += __shfl_xor(cs[ct], 32);
    }
    if (l < 16) {
#pragma unroll
        for (int ct = 0; ct < 4; ++ct) part[w][ct * 16 + l] = cs[ct];
    }
    __syncthreads();
    if (t < 64) {
        float dia = part[0][t] + part[1][t] + part[2][t] + part[3][t];
        float tot = dia;
#pragma unroll
        for (int off = 1; off < 64; off <<= 1) tot += __shfl_xor(tot, off);
        dia = fmaxf(dia, tot / 100000.0f);
        dia = fmaxf(dia, 1e-5f);
        invs[t] = rsqrtf(dia);
    }
    __syncthreads();

    // A[m][n] = e*inv*inv -> P1 hi-only (Z1 dead; softmax barriers fence)
    {
        int m0 = w * 16 + (l >> 4) * 4;
        float ir[4] = {invs[m0], invs[m0 + 1], invs[m0 + 2], invs[m0 + 3]};
        int nb = l & 15;
#pragma unroll
        for (int ct = 0; ct < 4; ++ct) {
            float ic = invs[ct * 16 + nb];
            short4v h;
#pragma unroll
            for (int r = 0; r < 4; ++r)
                h[r] = f2bf(e[ct][r] * ir[r] * ic);
            *(short4v*)&P[1][(ct * 16 + nb) * PITCH + m0] = h;
        }
    }
    __syncthreads();

    // z4 = V(global) · A^T -> pack into P0 (Kt dead)
    p1_g(vh, P[1], w, l, acc);
    pack1(acc, P[0], w, l);
    __syncthreads();

    // OUT = A · z4^T = A V A^T
    p1(P[1], P[0], w, l, acc);
    __syncthreads();   // all plane reads done; alias as f32 out-stage

    // stage out tile f32 [64][68] over P (17,408 B of 18,432), then store
    {
        float* ofs = (float*)&P[0][0];
        int m0 = w * 16 + (l >> 4) * 4;
        int nb = l & 15;
#pragma unroll
        for (int ct = 0; ct < 4; ++ct)
#pragma unroll
            for (int r = 0; r < 4; ++r)
                ofs[(m0 + r) * 68 + ct * 16 + nb] = acc[ct][r];
    }
    __syncthreads();
    {
        const float* ofs = (const float*)&P[0][0];
#pragma unroll
        for (int rep = 0; rep < 4; ++rep) {
            int id = rep * 256 + t;
            int row = id >> 4, c4 = (id & 15) * 4;
            float4 v  = *(const float4*)&ofs[row * 68 + c4];
            float4 xv = *(const float4*)&x[gbase + (size_t)row * 64 + c4];
            *(float4*)&out[gbase + (size_t)row * 64 + c4] =
                make_float4(xv.x + v.x, xv.y + v.y, xv.z + v.z, xv.w + v.w);
        }
    }
}

// ---------------- launch -----------------------------------------------------
extern "C" void kernel_launch(void* const* d_in, const int* in_sizes, int n_in,
                              void* d_out, int out_size, void* d_ws, size_t ws_size,
                              hipStream_t stream) {
    const float* x  = (const float*)d_in[0];
    const float* wq = (const float*)d_in[1];
    const float* wk = (const float*)d_in[2];
    const float* wv = (const float*)d_in[3];
    float* out = (float*)d_out;

    char* wsb = (char*)d_ws;
    float* invd = (float*)wsb;                       // 1 MB
    short* w3h  = (short*)(wsb + (1 << 20));         // 24 KB
    short* QKV  = (short*)(wsb + (2 << 20));         // 96 MB, [n][i][192ch][j]

    k0_prep<<<1072, 256, 0, stream>>>(x, wq, wk, wv, invd, w3h);
    k1_mix_mfma<<<2048, 256, 0, stream>>>(x, invd, w3h, QKV);
    k2_attn_mfma<<<4096, 256, 0, stream>>>(x, QKV, out);
}

// Round 13
// 78.930 us; speedup vs baseline: 2.1938x; 1.0130x over previous
//
#include <hip/hip_runtime.h>

#define PITCH 72   // bf16 pitch for MFMA planes: 144 B rows, 16B-aligned
#define QKV_STRIDE 12288   // shorts per (n,i): 192 ch x 64 j

typedef __attribute__((ext_vector_type(8))) short short8v;
typedef __attribute__((ext_vector_type(4))) short short4v;
typedef __attribute__((ext_vector_type(4))) float f32x4;

// ---------------- bf16 helpers -----------------------------------------------
__device__ __forceinline__ short f2bf(float v) {
    unsigned u = __builtin_bit_cast(unsigned, v);
    unsigned r = (u + 0x7FFFu + ((u >> 16) & 1u)) >> 16;
    return (short)r;
}
__device__ __forceinline__ float bf2f(short s) {
    unsigned u = ((unsigned)(unsigned short)s) << 16;
    return __builtin_bit_cast(float, u);
}

#define MFMA(a, b, c) __builtin_amdgcn_mfma_f32_16x16x32_bf16(a, b, c, 0, 0, 0)

// A/B fragment from LDS plane (pitch 72)
__device__ __forceinline__ short8v ldfrag(const short* p, int rowtile, int kc, int l) {
    return *(const short8v*)&p[(rowtile * 16 + (l & 15)) * PITCH + kc * 32 + (l >> 4) * 8];
}
// fragment from global row-major [rows][64]
__device__ __forceinline__ short8v gfrag(const short* __restrict__ p, int rowtile, int kc, int l) {
    return *(const short8v*)&p[(rowtile * 16 + (l & 15)) * 64 + kc * 32 + (l >> 4) * 8];
}
// fragment from global with custom row stride (for [n][i][ch][j] gathers)
__device__ __forceinline__ short8v gfrag_s(const short* __restrict__ p, int rowtile,
                                           int kc, int l, int stride) {
    return *(const short8v*)&p[(rowtile * 16 + (l & 15)) * stride + kc * 32 + (l >> 4) * 8];
}

// D = X·Y^T, hi-only, X,Y in LDS
__device__ __forceinline__ void p1(const short* xh, const short* yh,
                                   int w, int l, f32x4 (&acc)[4]) {
#pragma unroll
    for (int ct = 0; ct < 4; ++ct) acc[ct] = (f32x4){0.f, 0.f, 0.f, 0.f};
#pragma unroll
    for (int kc = 0; kc < 2; ++kc) {
        short8v aH = ldfrag(xh, w, kc, l);
#pragma unroll
        for (int ct = 0; ct < 4; ++ct)
            acc[ct] = MFMA(aH, ldfrag(yh, ct, kc, l), acc[ct]);
    }
}

// D = X·Y^T, hi-only, X from GLOBAL with row stride
__device__ __forceinline__ void p1_g(const short* __restrict__ xg, const short* yh,
                                     int w, int l, f32x4 (&acc)[4]) {
#pragma unroll
    for (int ct = 0; ct < 4; ++ct) acc[ct] = (f32x4){0.f, 0.f, 0.f, 0.f};
#pragma unroll
    for (int kc = 0; kc < 2; ++kc) {
        short8v aH = gfrag_s(xg, w, kc, l, QKV_STRIDE);
#pragma unroll
        for (int ct = 0; ct < 4; ++ct)
            acc[ct] = MFMA(aH, ldfrag(yh, ct, kc, l), acc[ct]);
    }
}

// pack-store D transposed, hi only: z[n][m] = bf16(D[m][n])
__device__ __forceinline__ void pack1(const f32x4 (&acc)[4], short* zh, int w, int l) {
    int m0 = w * 16 + (l >> 4) * 4;
#pragma unroll
    for (int ct = 0; ct < 4; ++ct) {
        int n = ct * 16 + (l & 15);
        short4v h;
#pragma unroll
        for (int r = 0; r < 4; ++r) h[r] = f2bf(acc[ct][r]);
        *(short4v*)&zh[n * PITCH + m0] = h;
    }
}

// in-place exact transpose of ONE plane via identity-MFMA (1 internal barrier)
__device__ __forceinline__ void idtrans_ip1(short* pa, int w, int l) {
    short8v a0 = ldfrag(pa, w, 0, l);
    short8v a1 = ldfrag(pa, w, 1, l);
    short8v I0, I1;
#pragma unroll
    for (int j = 0; j < 8; ++j) {
        int bit = 8 * (l >> 4) + j;
        I0[j] = (bit == (l & 15))      ? (short)0x3F80 : (short)0;
        I1[j] = (bit == (l & 15) + 16) ? (short)0x3F80 : (short)0;
    }
    __syncthreads();
    int m0 = w * 16 + (l >> 4) * 4;
    const f32x4 z4 = {0.f, 0.f, 0.f, 0.f};
#pragma unroll
    for (int s = 0; s < 4; ++s) {
        f32x4 d = MFMA((s >> 1) ? a1 : a0, (s & 1) ? I1 : I0, z4);
        short4v ha;
#pragma unroll
        for (int r = 0; r < 4; ++r) ha[r] = f2bf(d[r]);   // exact: values are bf16
        *(short4v*)&pa[(s * 16 + (l & 15)) * PITCH + m0] = ha;
    }
}

// ---------------- K0: inv_diag + w3T (merged) ---------------------------------
__global__ __launch_bounds__(256) void k0_prep(const float* __restrict__ x,
                                               const float* __restrict__ wq,
                                               const float* __restrict__ wk,
                                               const float* __restrict__ wv,
                                               float* __restrict__ invd,
                                               short* __restrict__ w3h) {
    int b = blockIdx.x;
    if (b < 1024) {
        int t = b * 256 + threadIdx.x;
        int nc = t >> 6, k = t & 63;
        float v = fabsf(x[(size_t)nc * 4096 + (size_t)k * 65]);
        invd[t] = rsqrtf(fmaxf(v, 1e-4f));
    } else {
        int idx = (b - 1024) * 256 + threadIdx.x;   // [0, 12288)
        int co = idx >> 6, c = idx & 63;
        const float* w = (co < 64) ? wq : (co < 128) ? wk : wv;
        w3h[idx] = f2bf(w[c * 64 + (co & 63)]);
    }
}

// ---------------- K1: cov2cor + channel mixing (hi-only), slim LDS ------------
// Block (n,i). 13.8KB LDS (cor aliased by z[96][72]); two 96-row pack+copy
// passes; bounds(256,4) keeps VGPR cap 128 (R11 lesson: bound 8 -> cap 64 -> spill).
__global__ __launch_bounds__(256, 4) void k1_mix_mfma(
    const float* __restrict__ x, const float* __restrict__ invd,
    const short* __restrict__ w3h,
    short* __restrict__ QKV)
{
    __shared__ __align__(16) short smem[6912];    // 13,824 B; cor in [0,4608)
    short* ch = smem;

    const int b = blockIdx.x, n = b >> 6, i = b & 63;
    const int t = threadIdx.x, l = t & 63, w = t >> 6;
    const size_t nbase = (size_t)n * 64;

    // stage cor hi plane [c][j]
#pragma unroll
    for (int rep = 0; rep < 4; ++rep) {
        int id = rep * 256 + t;                 // 1024 float4 chunks
        int c = id >> 4, j4 = (id & 15) * 4;
        float4 xv = *(const float4*)&x[((nbase + c) * 64 + i) * 64 + j4];
        float ii = invd[(nbase + c) * 64 + i];
        float4 jv = *(const float4*)&invd[(nbase + c) * 64 + j4];
        float vv[4] = {xv.x * ii * jv.x, xv.y * ii * jv.y,
                       xv.z * ii * jv.z, xv.w * ii * jv.w};
        short4v h;
#pragma unroll
        for (int r = 0; r < 4; ++r)
            h[r] = f2bf(fminf(1.0f, fmaxf(-1.0f, vv[r])));
        *(short4v*)&ch[c * PITCH + j4] = h;
    }
    __syncthreads();
    idtrans_ip1(ch, w, l);       // cor -> corT in place (1 internal barrier)
    __syncthreads();

    // wave w: co-tiles ct = 3w..3w+2, all 4 j-tiles
    f32x4 acc[4][3];
#pragma unroll
    for (int jt = 0; jt < 4; ++jt)
#pragma unroll
        for (int cc = 0; cc < 3; ++cc) acc[jt][cc] = (f32x4){0.f, 0.f, 0.f, 0.f};
#pragma unroll
    for (int kc = 0; kc < 2; ++kc) {
#pragma unroll
        for (int cc = 0; cc < 3; ++cc) {
            short8v bH = gfrag(w3h, w * 3 + cc, kc, l);
#pragma unroll
            for (int jt = 0; jt < 4; ++jt) {
                short8v aH = ldfrag(ch, jt, kc, l);
                acc[jt][cc] = MFMA(aH, bH, acc[jt][cc]);
            }
        }
    }
    __syncthreads();   // all cor reads done; smem becomes z[96][72]

    const int m0 = (l >> 4) * 4, nb = l & 15;
    short* dst = QKV + (size_t)b * QKV_STRIDE;

    // ---- pass A: tiles 0..5 (waves 0,1) -> z rows 0..95; linear 12KB copy ----
    if (w < 2) {
#pragma unroll
        for (int cc = 0; cc < 3; ++cc) {
            int zrow = (w * 3 + cc) * 16 + nb;
#pragma unroll
            for (int jt = 0; jt < 4; ++jt) {
                short4v h;
#pragma unroll
                for (int r = 0; r < 4; ++r) h[r] = f2bf(acc[jt][cc][r]);
                *(short4v*)&smem[zrow * PITCH + jt * 16 + m0] = h;
            }
        }
    }
    __syncthreads();
#pragma unroll
    for (int rep = 0; rep < 3; ++rep) {
        int id = rep * 256 + t;                 // 768 chunks of 8 shorts
        *(short8v*)&dst[id * 8] = *(short8v*)&smem[(id >> 3) * PITCH + (id & 7) * 8];
    }
    __syncthreads();

    // ---- pass B: tiles 6..11 (waves 2,3) -> z rows 0..95; linear 12KB copy ----
    if (w >= 2) {
#pragma unroll
        for (int cc = 0; cc < 3; ++cc) {
            int zrow = ((w - 2) * 3 + cc) * 16 + nb;
#pragma unroll
            for (int jt = 0; jt < 4; ++jt) {
                short4v h;
#pragma unroll
                for (int r = 0; r < 4; ++r) h[r] = f2bf(acc[jt][cc][r]);
                *(short4v*)&smem[zrow * PITCH + jt * 16 + m0] = h;
            }
        }
    }
    __syncthreads();
#pragma unroll
    for (int rep = 0; rep < 3; ++rep) {
        int id = rep * 256 + t;
        *(short8v*)&dst[6144 + id * 8] =
            *(short8v*)&smem[(id >> 3) * PITCH + (id & 7) * 8];
    }
}

// ---------------- K2: per-(n,c) attention chain, 2 LDS planes -----------------
// Q,K,V,Z1,z4,A all hi-only bf16. bounds(256,5): VGPR cap 102, no spill risk.
__global__ __launch_bounds__(256, 5) void k2_attn_mfma(
    const float* __restrict__ x,
    const short* __restrict__ QKV,
    float* __restrict__ out)
{
    // P[0]: K -> Kt -> z4 ; P[1]: Z1 -> A
    __shared__ __align__(16) short P[2][4608];
    __shared__ float part[4][64];
    __shared__ float invs[64];
    __shared__ float red[4];

    const int t = threadIdx.x, l = t & 63, w = t >> 6;
    const int nc = blockIdx.x, n = nc >> 6, c = nc & 63;
    const size_t gbase = (size_t)nc * 4096;

    const short* qh = QKV + (size_t)n * 64 * QKV_STRIDE + (size_t)c * 64;
    const short* kh = qh + 64 * 64;          // ch = 64 + c
    const short* vh = qh + 128 * 64;         // ch = 128 + c

    // stage K hi (rows stride 24KB)
#pragma unroll
    for (int rep = 0; rep < 4; ++rep) {
        int id = rep * 256 + t;
        int r = id >> 4, c4 = (id & 15) * 4;
        *(short4v*)&P[0][r * PITCH + c4] =
            *(const short4v*)&kh[r * QKV_STRIDE + c4];
    }
    __syncthreads();

    idtrans_ip1(P[0], w, l);   // K -> Kt in place
    __syncthreads();

    f32x4 acc[4];

    // Z1 = Q(global) · Kt^T  -> pack into P1
    p1_g(qh, P[0], w, l, acc);
    pack1(acc, P[1], w, l);
    __syncthreads();

    // Pt = Z1 · Kt^T (in registers)
    p1(P[1], P[0], w, l, acc);

    // ---- soft_pd_max ----
    float mx = -1e30f;
#pragma unroll
    for (int ct = 0; ct < 4; ++ct)
#pragma unroll
        for (int r = 0; r < 4; ++r) mx = fmaxf(mx, acc[ct][r]);
#pragma unroll
    for (int off = 1; off < 64; off <<= 1) mx = fmaxf(mx, __shfl_xor(mx, off));
    if (l == 0) red[w] = mx;
    __syncthreads();
    mx = fmaxf(fmaxf(red[0], red[1]), fmaxf(red[2], red[3]));

    float e[4][4];
    float cs[4];
#pragma unroll
    for (int ct = 0; ct < 4; ++ct) {
        float s = 0.f;
#pragma unroll
        for (int r = 0; r < 4; ++r) {
            float ev = __expf(acc[ct][r] - mx);
            e[ct][r] = ev;
            s += ev;
        }
        cs[ct] = s;
    }
#pragma unroll
    for (int ct = 0; ct < 4; ++ct) {
        cs[ct] += __shfl_xor(cs[ct], 16);
        cs[ct] += __shfl_xor(cs[ct], 32);
    }
    if (l < 16) {
#pragma unroll
        for (int ct = 0; ct < 4; ++ct) part[w][ct * 16 + l] = cs[ct];
    }
    __syncthreads();
    if (t < 64) {
        float dia = part[0][t] + part[1][t] + part[2][t] + part[3][t];
        float tot = dia;
#pragma unroll
        for (int off = 1; off < 64; off <<= 1) tot += __shfl_xor(tot, off);
        dia = fmaxf(dia, tot / 100000.0f);
        dia = fmaxf(dia, 1e-5f);
        invs[t] = rsqrtf(dia);
    }
    __syncthreads();

    // A[m][n] = e*inv*inv -> P1 hi-only (Z1 dead; softmax barriers fence)
    {
        int m0 = w * 16 + (l >> 4) * 4;
        float ir[4] = {invs[m0], invs[m0 + 1], invs[m0 + 2], invs[m0 + 3]};
        int nb = l & 15;
#pragma unroll
        for (int ct = 0; ct < 4; ++ct) {
            float ic = invs[ct * 16 + nb];
            short4v h;
#pragma unroll
            for (int r = 0; r < 4; ++r)
                h[r] = f2bf(e[ct][r] * ir[r] * ic);
            *(short4v*)&P[1][(ct * 16 + nb) * PITCH + m0] = h;
        }
    }
    __syncthreads();

    // z4 = V(global) · A^T -> pack into P0 (Kt dead)
    p1_g(vh, P[1], w, l, acc);
    pack1(acc, P[0], w, l);
    __syncthreads();

    // OUT = A · z4^T = A V A^T
    p1(P[1], P[0], w, l, acc);
    __syncthreads();   // all plane reads done; alias as f32 out-stage

    // stage out tile f32 [64][68] over P (17,408 B of 18,432), then store
    {
        float* ofs = (float*)&P[0][0];
        int m0 = w * 16 + (l >> 4) * 4;
        int nb = l & 15;
#pragma unroll
        for (int ct = 0; ct < 4; ++ct)
#pragma unroll
            for (int r = 0; r < 4; ++r)
                ofs[(m0 + r) * 68 + ct * 16 + nb] = acc[ct][r];
    }
    __syncthreads();
    {
        const float* ofs = (const float*)&P[0][0];
#pragma unroll
        for (int rep = 0; rep < 4; ++rep) {
            int id = rep * 256 + t;
            int row = id >> 4, c4 = (id & 15) * 4;
            float4 v  = *(const float4*)&ofs[row * 68 + c4];
            float4 xv = *(const float4*)&x[gbase + (size_t)row * 64 + c4];
            *(float4*)&out[gbase + (size_t)row * 64 + c4] =
                make_float4(xv.x + v.x, xv.y + v.y, xv.z + v.z, xv.w + v.w);
        }
    }
}

// ---------------- launch -----------------------------------------------------
extern "C" void kernel_launch(void* const* d_in, const int* in_sizes, int n_in,
                              void* d_out, int out_size, void* d_ws, size_t ws_size,
                              hipStream_t stream) {
    const float* x  = (const float*)d_in[0];
    const float* wq = (const float*)d_in[1];
    const float* wk = (const float*)d_in[2];
    const float* wv = (const float*)d_in[3];
    float* out = (float*)d_out;

    char* wsb = (char*)d_ws;
    float* invd = (float*)wsb;                       // 1 MB
    short* w3h  = (short*)(wsb + (1 << 20));         // 24 KB
    short* QKV  = (short*)(wsb + (2 << 20));         // 96 MB, [n][i][192ch][j]

    k0_prep<<<1072, 256, 0, stream>>>(x, wq, wk, wv, invd, w3h);
    k1_mix_mfma<<<4096, 256, 0, stream>>>(x, invd, w3h, QKV);
    k2_attn_mfma<<<4096, 256, 0, stream>>>(x, QKV, out);
}